// Round 3
// baseline (2150.790 us; speedup 1.0000x reference)
//
#include <hip/hip_runtime.h>
#include <hip/hip_bf16.h>

#define NDIM 100
#define HDIM 16
#define CDIM 20
#define BN   256   // nodes per bucket
#define BSH  8     // log2(BN)

// ---------------- pass 1: bucket histogram (LDS-aggregated) ----------------

__global__ __launch_bounds__(256) void pass1_count(const int* __restrict__ dst,
                                                   int* __restrict__ bcnt,
                                                   int E, int NB, int EPB) {
    extern __shared__ int hist[];
    for (int i = threadIdx.x; i < NB; i += 256) hist[i] = 0;
    __syncthreads();
    int e0 = blockIdx.x * EPB;
    int e1 = min(e0 + EPB, E);
    for (int e = e0 + threadIdx.x; e < e1; e += 256)
        atomicAdd(&hist[dst[e] >> BSH], 1);
    __syncthreads();
    for (int i = threadIdx.x; i < NB; i += 256) {
        int c = hist[i];
        if (c) atomicAdd(&bcnt[i], c);
    }
}

// ---------------- bucket exclusive scan (single block, NB <= 4096) ----------------

__global__ __launch_bounds__(256) void scan_buckets(const int* __restrict__ bcnt,
                                                    int* __restrict__ bstart,
                                                    int* __restrict__ bcur, int NB) {
    __shared__ int part[256];
    int t = threadIdx.x;
    int per = (NB + 255) / 256;   // <= 16
    int base = t * per;
    int loc[16];
    int s = 0;
    for (int k = 0; k < per; ++k) {
        int idx = base + k;
        int v = (idx < NB) ? bcnt[idx] : 0;
        loc[k] = v;
        s += v;
    }
    part[t] = s;
    __syncthreads();
    for (int off = 1; off < 256; off <<= 1) {
        int add = (t >= off) ? part[t - off] : 0;
        __syncthreads();
        part[t] += add;
        __syncthreads();
    }
    int run = (t > 0) ? part[t - 1] : 0;
    for (int k = 0; k < per; ++k) {
        int idx = base + k;
        if (idx < NB) { bstart[idx] = run; bcur[idx] = run; }
        run += loc[k];
    }
    if (t == 255) bstart[NB] = run;   // == E
}

// ---------------- pass 2: place edges into bucket-ordered ebuf ----------------
// Per-block LDS histogram -> one global range reservation per touched bucket ->
// place via LDS cursors. Writes land in contiguous multi-edge runs.

__global__ __launch_bounds__(256) void pass2_place(const int* __restrict__ src,
                                                   const int* __restrict__ dst,
                                                   int* __restrict__ bcur,
                                                   int2* __restrict__ ebuf,
                                                   int E, int NB, int EPB) {
    extern __shared__ int lds[];
    int* hbase = lds;        // becomes reserved global base per bucket
    int* hcur  = lds + NB;   // local placement cursor
    for (int i = threadIdx.x; i < NB; i += 256) { hbase[i] = 0; hcur[i] = 0; }
    __syncthreads();
    int e0 = blockIdx.x * EPB;
    int e1 = min(e0 + EPB, E);
    for (int e = e0 + threadIdx.x; e < e1; e += 256)
        atomicAdd(&hbase[dst[e] >> BSH], 1);
    __syncthreads();
    for (int i = threadIdx.x; i < NB; i += 256) {
        int c = hbase[i];
        hbase[i] = c ? atomicAdd(&bcur[i], c) : 0;
    }
    __syncthreads();
    for (int e = e0 + threadIdx.x; e < e1; e += 256) {
        int d = dst[e];
        int b = d >> BSH;
        int ofs = atomicAdd(&hcur[b], 1);
        ebuf[hbase[b] + ofs] = make_int2(src[e], d);
    }
}

// ---------------- per-bucket degree -> dinv ----------------

__global__ __launch_bounds__(256) void bucket_dinv(const int2* __restrict__ ebuf,
                                                   const int* __restrict__ bstart,
                                                   float* __restrict__ dinv, int N) {
    __shared__ int hist[BN];
    hist[threadIdx.x] = 0;
    __syncthreads();
    int b = blockIdx.x;
    int s0 = bstart[b], s1 = bstart[b + 1];
    for (int e = s0 + threadIdx.x; e < s1; e += 256)
        atomicAdd(&hist[ebuf[e].y & (BN - 1)], 1);
    __syncthreads();
    int n = b * BN + threadIdx.x;
    if (n < N) dinv[n] = rsqrtf((float)(hist[threadIdx.x] + 1));  // +1 self-loop
}

// ---------------- xw1 = x @ W1  ([N,100] @ [100,16]) ----------------

__global__ __launch_bounds__(256) void xw1_kernel(const float* __restrict__ x,
                                                  const float* __restrict__ W1,
                                                  float* __restrict__ xw1, int N) {
    __shared__ float Ws[NDIM * HDIM];  // [k][j]
    for (int t = threadIdx.x; t < NDIM * HDIM; t += 256) Ws[t] = W1[t];
    __syncthreads();

    const int ln = threadIdx.x >> 2;
    const int q  = threadIdx.x & 3;
    const int node = blockIdx.x * 64 + ln;
    if (node >= N) return;

    const float4* xr  = reinterpret_cast<const float4*>(x + (size_t)node * NDIM);
    const float4* Ws4 = reinterpret_cast<const float4*>(Ws);

    float4 acc = make_float4(0.f, 0.f, 0.f, 0.f);
#pragma unroll
    for (int kk = 0; kk < NDIM / 4; ++kk) {
        float4 xv = xr[kk];
        float xs[4] = {xv.x, xv.y, xv.z, xv.w};
#pragma unroll
        for (int c = 0; c < 4; ++c) {
            float4 w = Ws4[(kk * 4 + c) * 4 + q];
            acc.x += xs[c] * w.x;
            acc.y += xs[c] * w.y;
            acc.z += xs[c] * w.z;
            acc.w += xs[c] * w.w;
        }
    }
    reinterpret_cast<float4*>(xw1 + (size_t)node * HDIM)[q] = acc;
}

// ---------------- layer 1 fused: bucket gather -> relu -> @W2 -> xw2 ----------------
// 16 lanes per edge (lane f owns feature f). LDS acc row stride 17 (conflict-free).

__global__ __launch_bounds__(256) void gather1_fused(const int2* __restrict__ ebuf,
                                                     const int* __restrict__ bstart,
                                                     const float* __restrict__ dinv,
                                                     const float* __restrict__ xw1,
                                                     const float* __restrict__ b1,
                                                     const float* __restrict__ W2,
                                                     float* __restrict__ xw2, int N) {
    __shared__ float acc[BN * 17];
    __shared__ float W2s[HDIM * CDIM];  // [k][c], as stored
    __shared__ float b1s[HDIM];
    for (int i = threadIdx.x; i < BN * 17; i += 256) acc[i] = 0.f;
    for (int i = threadIdx.x; i < HDIM * CDIM; i += 256) W2s[i] = W2[i];
    if (threadIdx.x < HDIM) b1s[threadIdx.x] = b1[threadIdx.x];
    __syncthreads();

    int b = blockIdx.x;
    int s0 = bstart[b], s1 = bstart[b + 1];
    int g = threadIdx.x >> 4;   // 16 edge-groups
    int f = threadIdx.x & 15;   // feature lane

    for (int e = s0 + g; e < s1; e += 16) {
        int2 ed = ebuf[e];                      // broadcast within group
        float v = dinv[ed.x] * xw1[(size_t)ed.x * HDIM + f];  // 64B coalesced row
        atomicAdd(&acc[(ed.y & (BN - 1)) * 17 + f], v);       // ds_add_f32
    }
    __syncthreads();

    int n = b * BN + threadIdx.x;   // thread t = local node t
    if (n >= N) return;
    float dn = dinv[n];
    float d2 = dn * dn;

    float h[HDIM];
    const float4* x4 = reinterpret_cast<const float4*>(xw1 + (size_t)n * HDIM);
#pragma unroll
    for (int c = 0; c < HDIM / 4; ++c) {
        float4 xv = x4[c];
        float xs[4] = {xv.x, xv.y, xv.z, xv.w};
#pragma unroll
        for (int k = 0; k < 4; ++k) {
            int j = 4 * c + k;
            float v = dn * acc[threadIdx.x * 17 + j] + d2 * xs[k] + b1s[j];
            h[j] = fmaxf(v, 0.f);
        }
    }

    float o[CDIM];
#pragma unroll
    for (int c = 0; c < CDIM; ++c) {
        float s = 0.f;
#pragma unroll
        for (int k = 0; k < HDIM; ++k) s += h[k] * W2s[k * CDIM + c];  // broadcast
        o[c] = s;
    }
    float4* o4 = reinterpret_cast<float4*>(xw2 + (size_t)n * CDIM);
#pragma unroll
    for (int c = 0; c < CDIM / 4; ++c)
        o4[c] = make_float4(o[4 * c], o[4 * c + 1], o[4 * c + 2], o[4 * c + 3]);
}

// ---------------- layer 2 fused: bucket gather -> bias -> log_softmax -> out ----------
// 16 lanes per edge; lanes 0..3 also handle features 16..19. Acc stride 21.

__global__ __launch_bounds__(256) void gather2_fused(const int2* __restrict__ ebuf,
                                                     const int* __restrict__ bstart,
                                                     const float* __restrict__ dinv,
                                                     const float* __restrict__ xw2,
                                                     const float* __restrict__ b2,
                                                     float* __restrict__ out, int N) {
    __shared__ float acc[BN * 21];
    __shared__ float b2s[CDIM];
    for (int i = threadIdx.x; i < BN * 21; i += 256) acc[i] = 0.f;
    if (threadIdx.x < CDIM) b2s[threadIdx.x] = b2[threadIdx.x];
    __syncthreads();

    int b = blockIdx.x;
    int s0 = bstart[b], s1 = bstart[b + 1];
    int g = threadIdx.x >> 4;
    int f = threadIdx.x & 15;

    for (int e = s0 + g; e < s1; e += 16) {
        int2 ed = ebuf[e];
        float ds = dinv[ed.x];
        int ld = (ed.y & (BN - 1)) * 21;
        const float* row = xw2 + (size_t)ed.x * CDIM;
        atomicAdd(&acc[ld + f], ds * row[f]);
        if (f < CDIM - HDIM) atomicAdd(&acc[ld + HDIM + f], ds * row[HDIM + f]);
    }
    __syncthreads();

    int n = b * BN + threadIdx.x;
    if (n >= N) return;
    float dn = dinv[n];
    float d2 = dn * dn;

    float t[CDIM];
    const float4* x4 = reinterpret_cast<const float4*>(xw2 + (size_t)n * CDIM);
#pragma unroll
    for (int c = 0; c < CDIM / 4; ++c) {
        float4 xv = x4[c];
        float xs[4] = {xv.x, xv.y, xv.z, xv.w};
#pragma unroll
        for (int k = 0; k < 4; ++k) {
            int j = 4 * c + k;
            t[j] = dn * acc[threadIdx.x * 21 + j] + d2 * xs[k] + b2s[j];
        }
    }
    float m = t[0];
#pragma unroll
    for (int j = 1; j < CDIM; ++j) m = fmaxf(m, t[j]);
    float s = 0.f;
#pragma unroll
    for (int j = 0; j < CDIM; ++j) s += __expf(t[j] - m);
    float l = __logf(s) + m;

    float4* o4 = reinterpret_cast<float4*>(out + (size_t)n * CDIM);
#pragma unroll
    for (int c = 0; c < CDIM / 4; ++c)
        o4[c] = make_float4(t[4 * c + 0] - l, t[4 * c + 1] - l,
                            t[4 * c + 2] - l, t[4 * c + 3] - l);
}

// ---------------- launch ----------------

extern "C" void kernel_launch(void* const* d_in, const int* in_sizes, int n_in,
                              void* d_out, int out_size, void* d_ws, size_t ws_size,
                              hipStream_t stream) {
    const float* x  = (const float*)d_in[0];
    const int* edge = (const int*)d_in[1];   // [2, E] int32
    const float* W1 = (const float*)d_in[2];
    const float* b1 = (const float*)d_in[3];
    const float* W2 = (const float*)d_in[4];
    const float* b2 = (const float*)d_in[5];
    float* out = (float*)d_out;

    const int N = in_sizes[0] / NDIM;   // 500000
    const int E = in_sizes[1] / 2;      // 8000000
    const int* src = edge;
    const int* dst = edge + E;

    const int NB = (N + BN - 1) >> BSH; // 1954 buckets
    const int EPB = 16384;              // edges per sort block
    const int nbE = (E + EPB - 1) / EPB;

    char* ws = (char*)d_ws;
    size_t off = 0;
    int2*  ebuf   = (int2*)(ws + off);  off += (size_t)E * 8;
    int*   bcnt   = (int*)(ws + off);   off += (size_t)(NB + 1) * 4;
    int*   bstart = (int*)(ws + off);   off += (size_t)(NB + 1) * 4;
    int*   bcur   = (int*)(ws + off);   off += (size_t)(NB + 1) * 4;
    float* dinv   = (float*)(ws + off); off += (size_t)N * 4;
    float* xw1    = (float*)(ws + off); off += (size_t)N * HDIM * 4;
    float* xw2    = (float*)(ws + off); off += (size_t)N * CDIM * 4;

    hipMemsetAsync(bcnt, 0, (size_t)NB * 4, stream);

    // bucket sort of edges by dst (coarse, 256 nodes per bucket)
    pass1_count<<<nbE, 256, NB * 4, stream>>>(dst, bcnt, E, NB, EPB);
    scan_buckets<<<1, 256, 0, stream>>>(bcnt, bstart, bcur, NB);
    pass2_place<<<nbE, 256, 2 * NB * 4, stream>>>(src, dst, bcur, ebuf, E, NB, EPB);

    // degree/dinv from bucketed edges
    bucket_dinv<<<NB, 256, 0, stream>>>(ebuf, bstart, dinv, N);

    // dense matmul xw1
    xw1_kernel<<<(N + 63) / 64, 256, 0, stream>>>(x, W1, xw1, N);

    // layer 1 (gather + relu + @W2 fused) -> xw2
    gather1_fused<<<NB, 256, 0, stream>>>(ebuf, bstart, dinv, xw1, b1, W2, xw2, N);

    // layer 2 (gather + bias + log_softmax fused) -> out
    gather2_fused<<<NB, 256, 0, stream>>>(ebuf, bstart, dinv, xw2, b2, out, N);
}